// Round 2
// baseline (1745.159 us; speedup 1.0000x reference)
//
#include <hip/hip_runtime.h>
#include <math.h>

#define N_NODES 20000
#define N_EDGES 320000

// ---------------------------------------------------------------------------
// Generic tiled fp32 GEMM: C[M,Nout] = act(A[M,K] @ W[Nout,K]^T + bias)
// BM=BN=64, BK=16, 256 threads, 4x4 micro-tile.
// ACT: 0 = none, 1 = tanh
// ---------------------------------------------------------------------------
template <int ACT>
__global__ __launch_bounds__(256) void gemm_kernel(
    const float* __restrict__ A, int lda,
    const float* __restrict__ W,
    const float* __restrict__ bias,
    float* __restrict__ C, int ldc,
    int M, int K)
{
    __shared__ float As[16][68];
    __shared__ float Ws[16][68];
    const int tid = threadIdx.x;
    const int tx = tid & 15;        // output col group
    const int ty = tid >> 4;        // output row group
    const int lr = tid >> 2;        // staging row 0..63
    const int lk = (tid & 3) << 2;  // staging k offset 0,4,8,12
    const int m0 = blockIdx.x * 64;
    const int n0 = blockIdx.y * 64;

    float acc[4][4] = {};

    for (int k0 = 0; k0 < K; k0 += 16) {
        int am = m0 + lr; if (am >= M) am = M - 1;   // clamp; stores guarded
        float4 av = *(const float4*)&A[(size_t)am * lda + k0 + lk];
        float4 wv = *(const float4*)&W[(size_t)(n0 + lr) * K + k0 + lk];
        __syncthreads();   // protect readers of previous chunk
        As[lk + 0][lr] = av.x; As[lk + 1][lr] = av.y;
        As[lk + 2][lr] = av.z; As[lk + 3][lr] = av.w;
        Ws[lk + 0][lr] = wv.x; Ws[lk + 1][lr] = wv.y;
        Ws[lk + 2][lr] = wv.z; Ws[lk + 3][lr] = wv.w;
        __syncthreads();
#pragma unroll
        for (int kk = 0; kk < 16; ++kk) {
            float4 a4 = *(const float4*)&As[kk][ty << 2];
            float4 w4 = *(const float4*)&Ws[kk][tx << 2];
            acc[0][0] = fmaf(a4.x, w4.x, acc[0][0]);
            acc[0][1] = fmaf(a4.x, w4.y, acc[0][1]);
            acc[0][2] = fmaf(a4.x, w4.z, acc[0][2]);
            acc[0][3] = fmaf(a4.x, w4.w, acc[0][3]);
            acc[1][0] = fmaf(a4.y, w4.x, acc[1][0]);
            acc[1][1] = fmaf(a4.y, w4.y, acc[1][1]);
            acc[1][2] = fmaf(a4.y, w4.z, acc[1][2]);
            acc[1][3] = fmaf(a4.y, w4.w, acc[1][3]);
            acc[2][0] = fmaf(a4.z, w4.x, acc[2][0]);
            acc[2][1] = fmaf(a4.z, w4.y, acc[2][1]);
            acc[2][2] = fmaf(a4.z, w4.z, acc[2][2]);
            acc[2][3] = fmaf(a4.z, w4.w, acc[2][3]);
            acc[3][0] = fmaf(a4.w, w4.x, acc[3][0]);
            acc[3][1] = fmaf(a4.w, w4.y, acc[3][1]);
            acc[3][2] = fmaf(a4.w, w4.z, acc[3][2]);
            acc[3][3] = fmaf(a4.w, w4.w, acc[3][3]);
        }
    }

    const int nb = n0 + (tx << 2);
    float b0 = bias[nb + 0], b1 = bias[nb + 1], b2 = bias[nb + 2], b3 = bias[nb + 3];
#pragma unroll
    for (int i = 0; i < 4; ++i) {
        int m = m0 + (ty << 2) + i;
        if (m >= M) continue;
        float4 v;
        v.x = acc[i][0] + b0; v.y = acc[i][1] + b1;
        v.z = acc[i][2] + b2; v.w = acc[i][3] + b3;
        if (ACT == 1) { v.x = tanhf(v.x); v.y = tanhf(v.y); v.z = tanhf(v.z); v.w = tanhf(v.w); }
        *(float4*)&C[(size_t)m * ldc + nb] = v;
    }
}

// ---------------------------------------------------------------------------
// Pack WPQ[512][128] and bPQ[512] from enc_w1 [256][256], enc_b1.
// Rows 0..255:  P-weights  w1[c][k] - w1[c][128+k], bias b1[c]
// Rows 256..511: Q-weights w1[c][128+k],            bias 0
// ---------------------------------------------------------------------------
__global__ void pack_wpq(const float* __restrict__ w1, const float* __restrict__ b1,
                         float* __restrict__ WPQ, float* __restrict__ bPQ)
{
    int idx = blockIdx.x * 256 + threadIdx.x;
    if (idx < 512 * 128) {
        int r = idx >> 7, k = idx & 127;
        WPQ[idx] = (r < 256) ? (w1[r * 256 + k] - w1[r * 256 + 128 + k])
                             : w1[(r - 256) * 256 + 128 + k];
    }
    if (idx < 512) bPQ[idx] = (idx < 256) ? b1[idx] : 0.0f;
}

// ---------------------------------------------------------------------------
// Fused edge kernel: per 64-edge tile,
//   h1[e][c] = relu(P[dst[e]][c] + Q[src[e]][c])   (built in LDS, [k][m] layout)
//   h2 = h1 @ W2^T + b2 ; agg[dst] = max(agg[dst], relu(h2)) via int atomicMax
// PQ: [N,512] (P = cols 0..255, Q = cols 256..511)
// Node indices are defensively clamped to [0, N) — if the harness hands us
// int64 indices misread as int32 we want a wrong answer, not a dead container.
// ---------------------------------------------------------------------------
__global__ __launch_bounds__(256) void edge_kernel(
    const float* __restrict__ PQ,
    const int* __restrict__ ei,           // [2,E]: src row 0, dst row 1
    const float* __restrict__ W2,         // [256,256]
    const float* __restrict__ b2,
    float* __restrict__ agg)              // [N,256], pre-zeroed
{
    __shared__ float h1s[256][68];        // [k][edge]
    __shared__ float Ws[16][68];
    __shared__ int s_dst[64];
    __shared__ int s_src[64];

    const int tid = threadIdx.x;
    const int e0 = blockIdx.x * 64;

    if (tid < 64) {
        int d = ei[N_EDGES + e0 + tid];
        s_dst[tid] = (d < 0) ? 0 : (d >= N_NODES ? N_NODES - 1 : d);
    } else if (tid < 128) {
        int s = ei[e0 + tid - 64];
        s_src[tid - 64] = (s < 0) ? 0 : (s >= N_NODES ? N_NODES - 1 : s);
    }
    __syncthreads();

    // build h1 tile: thread = channel, loop over edges (coalesced 1KB row reads)
#pragma unroll 4
    for (int e = 0; e < 64; ++e) {
        float p = PQ[(size_t)s_dst[e] * 512 + tid];
        float q = PQ[(size_t)s_src[e] * 512 + 256 + tid];
        h1s[tid][e] = fmaxf(p + q, 0.0f);
    }
    __syncthreads();

    const int tx = tid & 15;
    const int ty = tid >> 4;
    const int lr = tid >> 2;
    const int lk = (tid & 3) << 2;

    for (int n0 = 0; n0 < 256; n0 += 64) {
        float acc[4][4] = {};
        for (int k0 = 0; k0 < 256; k0 += 16) {
            float4 wv = *(const float4*)&W2[(size_t)(n0 + lr) * 256 + k0 + lk];
            __syncthreads();
            Ws[lk + 0][lr] = wv.x; Ws[lk + 1][lr] = wv.y;
            Ws[lk + 2][lr] = wv.z; Ws[lk + 3][lr] = wv.w;
            __syncthreads();
#pragma unroll
            for (int kk = 0; kk < 16; ++kk) {
                float4 a4 = *(const float4*)&h1s[k0 + kk][ty << 2];
                float4 w4 = *(const float4*)&Ws[kk][tx << 2];
                acc[0][0] = fmaf(a4.x, w4.x, acc[0][0]);
                acc[0][1] = fmaf(a4.x, w4.y, acc[0][1]);
                acc[0][2] = fmaf(a4.x, w4.z, acc[0][2]);
                acc[0][3] = fmaf(a4.x, w4.w, acc[0][3]);
                acc[1][0] = fmaf(a4.y, w4.x, acc[1][0]);
                acc[1][1] = fmaf(a4.y, w4.y, acc[1][1]);
                acc[1][2] = fmaf(a4.y, w4.z, acc[1][2]);
                acc[1][3] = fmaf(a4.y, w4.w, acc[1][3]);
                acc[2][0] = fmaf(a4.z, w4.x, acc[2][0]);
                acc[2][1] = fmaf(a4.z, w4.y, acc[2][1]);
                acc[2][2] = fmaf(a4.z, w4.z, acc[2][2]);
                acc[2][3] = fmaf(a4.z, w4.w, acc[2][3]);
                acc[3][0] = fmaf(a4.w, w4.x, acc[3][0]);
                acc[3][1] = fmaf(a4.w, w4.y, acc[3][1]);
                acc[3][2] = fmaf(a4.w, w4.z, acc[3][2]);
                acc[3][3] = fmaf(a4.w, w4.w, acc[3][3]);
            }
        }
        const int nb = n0 + (tx << 2);
        float bb0 = b2[nb + 0], bb1 = b2[nb + 1], bb2 = b2[nb + 2], bb3 = b2[nb + 3];
#pragma unroll
        for (int i = 0; i < 4; ++i) {
            int e = (ty << 2) + i;
            int node = s_dst[e];
            float v0 = acc[i][0] + bb0;
            float v1 = acc[i][1] + bb1;
            float v2 = acc[i][2] + bb2;
            float v3 = acc[i][3] + bb3;
            int* arow = (int*)&agg[(size_t)node * 256 + nb];
            if (v0 > 0.0f) atomicMax(arow + 0, __float_as_int(v0));
            if (v1 > 0.0f) atomicMax(arow + 1, __float_as_int(v1));
            if (v2 > 0.0f) atomicMax(arow + 2, __float_as_int(v2));
            if (v3 > 0.0f) atomicMax(arow + 3, __float_as_int(v3));
        }
    }
}

// feat[N,288] = [agg | t | a]
__global__ void build_feat(const float* __restrict__ agg, const float* __restrict__ t,
                           const float* __restrict__ a, float* __restrict__ feat)
{
    int idx = blockIdx.x * 256 + threadIdx.x;
    if (idx >= N_NODES * 288) return;
    int n = idx / 288, c = idx - n * 288;
    float v;
    if (c < 256)      v = agg[(size_t)n * 256 + c];
    else if (c < 272) v = t[(size_t)n * 16 + (c - 256)];
    else              v = a[(size_t)n * 16 + (c - 272)];
    feat[idx] = v;
}

// GRU combine: hnew = (1-z)*tanh(i_n + r*h_n) + z*h
__global__ void gru_combine(const float* __restrict__ gi, const float* __restrict__ gh,
                            const float* __restrict__ hprev, float* __restrict__ hnew)
{
    int idx = blockIdx.x * 256 + threadIdx.x;
    if (idx >= N_NODES * 256) return;
    int n = idx >> 8, c = idx & 255;
    const float* gir = gi + (size_t)n * 768;
    const float* ghr = gh + (size_t)n * 768;
    float i_r = gir[c], i_z = gir[256 + c], i_n = gir[512 + c];
    float h_r = ghr[c], h_z = ghr[256 + c], h_n = ghr[512 + c];
    float r  = 1.0f / (1.0f + expf(-(i_r + h_r)));
    float zg = 1.0f / (1.0f + expf(-(i_z + h_z)));
    float nn = tanhf(i_n + r * h_n);
    float h  = hprev[idx];
    hnew[idx] = (1.0f - zg) * nn + zg * h;
}

// z = mu + eps * exp(0.5*log_var)
__global__ void z_kernel(const float* __restrict__ mu, const float* __restrict__ lv,
                         const float* __restrict__ eps, float* __restrict__ z)
{
    int idx = blockIdx.x * 256 + threadIdx.x;
    if (idx >= N_NODES * 64) return;
    z[idx] = mu[idx] + eps[idx] * expf(0.5f * lv[idx]);
}

extern "C" void kernel_launch(void* const* d_in, const int* in_sizes, int n_in,
                              void* d_out, int out_size, void* d_ws, size_t ws_size,
                              hipStream_t stream)
{
    const float* x      = (const float*)d_in[0];
    const float* t      = (const float*)d_in[1];
    const float* a      = (const float*)d_in[2];
    const float* eps    = (const float*)d_in[3];
    const int*   ei     = (const int*)d_in[4];
    const float* enc_w1 = (const float*)d_in[5];
    const float* enc_b1 = (const float*)d_in[6];
    const float* enc_w2 = (const float*)d_in[7];
    const float* enc_b2 = (const float*)d_in[8];
    const float* hi_w0  = (const float*)d_in[9];
    const float* hi_b0  = (const float*)d_in[10];
    const float* hi_w1  = (const float*)d_in[11];
    const float* hi_b1  = (const float*)d_in[12];
    const float* wih0   = (const float*)d_in[13];
    const float* whh0   = (const float*)d_in[14];
    const float* bih0   = (const float*)d_in[15];
    const float* bhh0   = (const float*)d_in[16];
    const float* wih1   = (const float*)d_in[17];
    const float* whh1   = (const float*)d_in[18];
    const float* bih1   = (const float*)d_in[19];
    const float* bhh1   = (const float*)d_in[20];
    const float* mu_w   = (const float*)d_in[21];
    const float* mu_b   = (const float*)d_in[22];
    const float* lv_w   = (const float*)d_in[23];
    const float* lv_b   = (const float*)d_in[24];

    // workspace layout (floats), peak 46,786,048 floats = 187.1 MB
    float* ws   = (float*)d_ws;
    float* WPQ  = ws;                      //      65,536
    float* bPQ  = ws + 65536;              //         512
    float* B    = ws + 66048;              //  15,360,000: PQ -> gi0 -> gi1
    float* C_   = ws + 15426048;           //   5,120,000: agg -> h0
    float* D_   = ws + 20546048;           //   5,760,000: feat
    float* E_   = ws + 26306048;           //   5,120,000: h1
    float* F_   = ws + 31426048;           //  15,360,000: gh0 -> gh1

    float* PQ   = B;
    float* agg  = C_;
    float* feat = D_;
    float* h0   = C_;    // reuse after build_feat consumed agg
    float* h1   = E_;
    float* gi0  = B;     // reuse after edge_kernel consumed PQ
    float* gh0  = F_;
    float* gi1  = B;
    float* gh1  = F_;

    float* out_h0 = (float*)d_out;                     // new_h0  [N,256]
    float* out_h1 = out_h0 + (size_t)N_NODES * 256;    // new_h1  [N,256]
    float* out_mu = out_h1 + (size_t)N_NODES * 256;    // mu      [N,64]
    float* out_lv = out_mu + (size_t)N_NODES * 64;     // log_var [N,64]
    float* out_z  = out_lv + (size_t)N_NODES * 64;     // z       [N,64]

    dim3 blk(256);

    hipMemsetAsync(agg, 0, (size_t)N_NODES * 256 * sizeof(float), stream);
    pack_wpq<<<(512 * 128 + 255) / 256, blk, 0, stream>>>(enc_w1, enc_b1, WPQ, bPQ);

    // PQ = x @ WPQ^T + bPQ   [N,512]
    gemm_kernel<0><<<dim3(313, 8), blk, 0, stream>>>(x, 128, WPQ, bPQ, PQ, 512, N_NODES, 128);

    // edge MLP layer 2 + segment-max
    edge_kernel<<<5000, blk, 0, stream>>>(PQ, ei, enc_w2, enc_b2, agg);

    build_feat<<<(N_NODES * 288 + 255) / 256, blk, 0, stream>>>(agg, t, a, feat);

    // NOTE: h0 GEMM writes over the agg region — agg is dead after build_feat
    gemm_kernel<1><<<dim3(313, 4), blk, 0, stream>>>(feat, 288, hi_w0, hi_b0, h0, 256, N_NODES, 288);
    gemm_kernel<1><<<dim3(313, 4), blk, 0, stream>>>(feat, 288, hi_w1, hi_b1, h1, 256, N_NODES, 288);
    // gi0 overwrites PQ region — PQ is dead after edge_kernel
    gemm_kernel<0><<<dim3(313, 12), blk, 0, stream>>>(feat, 288, wih0, bih0, gi0, 768, N_NODES, 288);
    gemm_kernel<0><<<dim3(313, 12), blk, 0, stream>>>(h0, 256, whh0, bhh0, gh0, 768, N_NODES, 256);
    gru_combine<<<(N_NODES * 256 + 255) / 256, blk, 0, stream>>>(gi0, gh0, h0, out_h0);

    gemm_kernel<0><<<dim3(313, 12), blk, 0, stream>>>(out_h0, 256, wih1, bih1, gi1, 768, N_NODES, 256);
    gemm_kernel<0><<<dim3(313, 12), blk, 0, stream>>>(h1, 256, whh1, bhh1, gh1, 768, N_NODES, 256);
    gru_combine<<<(N_NODES * 256 + 255) / 256, blk, 0, stream>>>(gi1, gh1, h1, out_h1);

    // heads
    gemm_kernel<0><<<dim3(313, 1), blk, 0, stream>>>(out_h1, 256, mu_w, mu_b, out_mu, 64, N_NODES, 256);
    gemm_kernel<0><<<dim3(313, 1), blk, 0, stream>>>(out_h1, 256, lv_w, lv_b, out_lv, 64, N_NODES, 256);
    z_kernel<<<(N_NODES * 64 + 255) / 256, blk, 0, stream>>>(out_mu, out_lv, eps, out_z);
}

// Round 4
// 946.070 us; speedup vs baseline: 1.8446x; 1.8446x over previous
//
#include <hip/hip_runtime.h>
#include <math.h>

#define N_NODES 20000
#define N_EDGES 320000

typedef __attribute__((ext_vector_type(8))) short bf16x8;
typedef __attribute__((ext_vector_type(4))) float f32x4;
typedef unsigned short ushort_t;
typedef unsigned int uint_t;

__device__ __forceinline__ float bf2f(uint_t u) {
    uint_t i = u << 16; float f; __builtin_memcpy(&f, &i, 4); return f;
}
__device__ __forceinline__ ushort_t f2bf(float f) {
    uint_t i; __builtin_memcpy(&i, &f, 4);
    uint_t r = i + 0x7fffu + ((i >> 16) & 1u);
    return (ushort_t)(r >> 16);
}

// ---------------------------------------------------------------------------
// Pack all weights into MFMA fragment order, bf16:
// layout per weight: [k0 = K/32][ot = NO/16][lane = 64][8 bf16]
// lane's 8 elems = W[row = ot*16 + (lane&15)][k = k0*32 + (lane>>4)*8 + j]
// Job 0 builds WPQ (P/Q transform of enc_w1); job 10 builds bPQ bias.
// ---------------------------------------------------------------------------
__global__ void pack_all(const float* __restrict__ w1, const float* __restrict__ b1,
                         const float* __restrict__ w2,
                         const float* __restrict__ hiw0, const float* __restrict__ hiw1,
                         const float* __restrict__ wih0, const float* __restrict__ whh0,
                         const float* __restrict__ wih1, const float* __restrict__ whh1,
                         const float* __restrict__ muw, const float* __restrict__ lvw,
                         ushort_t* __restrict__ pk, float* __restrict__ bpq)
{
    const int w = blockIdx.y;
    const int i = blockIdx.x * 256 + threadIdx.x;
    if (w == 10) { if (i < 512) bpq[i] = (i < 256) ? b1[i] : 0.0f; return; }
    const int Ks[10]  = {128, 256, 288, 288, 288, 256, 256, 256, 256, 256};
    const int NOs[10] = {512, 256, 256, 256, 768, 768, 768, 768, 64, 64};
    const int DST[10] = {0, 65536, 131072, 204800, 278528, 499712, 696320, 892928, 1089536, 1105920};
    const float* srcs[10] = {w1, w2, hiw0, hiw1, wih0, whh0, wih1, whh1, muw, lvw};
    const int K = Ks[w], NO = NOs[w];
    if (i >= (K * NO) >> 3) return;
    const int lane = i & 63, rest = i >> 6, NOT = NO >> 4;
    const int ot = rest % NOT, k0 = rest / NOT;
    const int row = ot * 16 + (lane & 15);
    const int kb = k0 * 32 + (lane >> 4) * 8;
    ushort_t o[8];
    if (w == 0) {
#pragma unroll
        for (int j = 0; j < 8; ++j) {
            int k = kb + j;
            float v = (row < 256) ? (w1[row * 256 + k] - w1[row * 256 + 128 + k])
                                  : w1[(row - 256) * 256 + 128 + k];
            o[j] = f2bf(v);
        }
    } else {
        const float* s = srcs[w];
#pragma unroll
        for (int j = 0; j < 8; ++j) o[j] = f2bf(s[(size_t)row * K + kb + j]);
    }
    ushort_t* d = pk + DST[w] + (size_t)i * 8;
    uint_t u0 = (uint_t)o[0] | ((uint_t)o[1] << 16);
    uint_t u1 = (uint_t)o[2] | ((uint_t)o[3] << 16);
    uint_t u2 = (uint_t)o[4] | ((uint_t)o[5] << 16);
    uint_t u3 = (uint_t)o[6] | ((uint_t)o[7] << 16);
    ((uint_t*)d)[0] = u0; ((uint_t*)d)[1] = u1; ((uint_t*)d)[2] = u2; ((uint_t*)d)[3] = u3;
}

// x f32 -> bf16
__global__ void xcvt(const float* __restrict__ x, ushort_t* __restrict__ xbf)
{
    int base = (blockIdx.x * 256 + threadIdx.x) * 4;
    if (base >= N_NODES * 128) return;
    float4 v = *(const float4*)&x[base];
    uint_t a = (uint_t)f2bf(v.x) | ((uint_t)f2bf(v.y) << 16);
    uint_t b = (uint_t)f2bf(v.z) | ((uint_t)f2bf(v.w) << 16);
    uint2 u; u.x = a; u.y = b;
    *(uint2*)&xbf[base] = u;
}

// ---------------------------------------------------------------------------
// MFMA GEMM: C[M, Ncols] = act(Abf[M,K](bf16) @ W^T + bias)
// BM=64, BN template (256 or 64), 256 thr / 4 waves, wave = 16 rows x BN cols.
// A staged to LDS bf16, XOR-swizzled (row&7)<<4 to kill ds_read_b128 conflicts.
// W pre-packed fragment-order (see pack_all). OMODE: 0=f32, 1=bf16, 2=dual+tanh
// ---------------------------------------------------------------------------
template <int BN, int OMODE>
__global__ __launch_bounds__(256) void mgemm(
    const ushort_t* __restrict__ Abf, int lda, int M, int K,
    const ushort_t* __restrict__ Wp, int NOtot, const float* __restrict__ bias,
    float* __restrict__ Cf, ushort_t* __restrict__ Cbf, int ldc)
{
    __shared__ char smem[40960];   // 64 rows x up to 640B (K=288 padded)
    const int tid = threadIdx.x;
    const int l = tid & 63, wid = tid >> 6;
    const int m0 = blockIdx.x * 64;
    const int n0 = blockIdx.y * BN;
    const int RS = (K * 2 + 127) & ~127;
    const int CHR = K >> 3;                  // 16B chunks per row
    for (int c = tid; c < 64 * CHR; c += 256) {
        int row = c / CHR, cb = c - row * CHR;
        int gr = m0 + row; if (gr >= M) gr = M - 1;
        bf16x8 v = *(const bf16x8*)&Abf[(size_t)gr * lda + cb * 8];
        *(bf16x8*)&smem[row * RS + ((cb * 16) ^ ((row & 7) << 4))] = v;
    }
    __syncthreads();

    constexpr int NT = BN / 16;
    f32x4 acc[NT];
#pragma unroll
    for (int j = 0; j < NT; ++j) acc[j] = (f32x4){0.f, 0.f, 0.f, 0.f};
    const int rw = wid * 16 + (l & 15);
    const int hi = l >> 4;
    const int swz = (rw & 7) << 4;
    const int KB = K >> 5;
    const int otb = n0 >> 4;
    for (int k0 = 0; k0 < KB; ++k0) {
        bf16x8 a = *(const bf16x8*)&smem[rw * RS + ((k0 * 64 + hi * 16) ^ swz)];
        const ushort_t* wb = Wp + ((size_t)(k0 * NOtot + otb) * 64 + l) * 8;
#pragma unroll
        for (int j = 0; j < NT; ++j) {
            bf16x8 b = *(const bf16x8*)&wb[(size_t)j * 512];
            acc[j] = __builtin_amdgcn_mfma_f32_16x16x32_bf16(a, b, acc[j], 0, 0, 0);
        }
    }
    const int c0 = l & 15;
    const int r0 = m0 + wid * 16 + hi * 4;
#pragma unroll
    for (int j = 0; j < NT; ++j) {
        float bj = bias[n0 + j * 16 + c0];
#pragma unroll
        for (int r = 0; r < 4; ++r) {
            int gr = r0 + r;
            if (gr >= M) continue;
            float v = acc[j][r] + bj;
            if (OMODE == 2) v = tanhf(v);
            size_t o = (size_t)gr * ldc + n0 + j * 16 + c0;
            if (OMODE == 0) Cf[o] = v;
            else if (OMODE == 1) Cbf[o] = f2bf(v);
            else { Cf[o] = v; Cbf[o] = f2bf(v); }
        }
    }
}

// ---------------------------------------------------------------------------
// Edge kernel (MFMA): 64 edges/block.
//   h1[e][c] = relu(P[dst][c] + Q[src][c]) built in LDS bf16 (swizzled)
//   h2 = h1 @ W2^T + b2 ; relu + segment-max via int atomicMax (agg >= 0)
// ---------------------------------------------------------------------------
__global__ __launch_bounds__(256) void edge_mfma(
    const ushort_t* __restrict__ PQbf,     // [N,512] bf16: P | Q
    const int* __restrict__ ei,
    const ushort_t* __restrict__ W2p,      // packed fragment order
    const float* __restrict__ b2,
    float* __restrict__ agg)               // [N,256] f32, pre-zeroed
{
    __shared__ char h1s[32768];            // 64 x 512B
    __shared__ int s_dst[64], s_src[64];
    const int tid = threadIdx.x;
    const int e0 = blockIdx.x * 64;
    if (tid < 64) {
        int d = ei[N_EDGES + e0 + tid];
        s_dst[tid] = min(max(d, 0), N_NODES - 1);
    } else if (tid < 128) {
        int s = ei[e0 + tid - 64];
        s_src[tid - 64] = min(max(s, 0), N_NODES - 1);
    }
    __syncthreads();

    const int er = tid >> 7, p2 = tid & 127;    // 2 edges in parallel
#pragma unroll 4
    for (int eb = 0; eb < 64; eb += 2) {
        int e = eb + er;
        uint_t pu = *(const uint_t*)&PQbf[(size_t)s_dst[e] * 512 + p2 * 2];
        uint_t qu = *(const uint_t*)&PQbf[(size_t)s_src[e] * 512 + 256 + p2 * 2];
        float v0 = fmaxf(bf2f(pu & 0xffffu) + bf2f(qu & 0xffffu), 0.f);
        float v1 = fmaxf(bf2f(pu >> 16) + bf2f(qu >> 16), 0.f);
        uint_t hv = (uint_t)f2bf(v0) | ((uint_t)f2bf(v1) << 16);
        *(uint_t*)&h1s[e * 512 + ((p2 * 4) ^ ((e & 7) << 4))] = hv;
    }
    __syncthreads();

    const int l = tid & 63, wid = tid >> 6;
    const int rw = wid * 16 + (l & 15);
    const int hi = l >> 4;
    const int swz = (rw & 7) << 4;
    f32x4 acc[16];
#pragma unroll
    for (int j = 0; j < 16; ++j) acc[j] = (f32x4){0.f, 0.f, 0.f, 0.f};
    for (int k0 = 0; k0 < 8; ++k0) {
        bf16x8 a = *(const bf16x8*)&h1s[rw * 512 + ((k0 * 64 + hi * 16) ^ swz)];
        const ushort_t* wb = W2p + ((size_t)(k0 * 16) * 64 + l) * 8;
#pragma unroll
        for (int j = 0; j < 16; ++j) {
            bf16x8 b = *(const bf16x8*)&wb[(size_t)j * 512];
            acc[j] = __builtin_amdgcn_mfma_f32_16x16x32_bf16(a, b, acc[j], 0, 0, 0);
        }
    }
    const int c0 = l & 15;
    const int edg = wid * 16 + hi * 4;
#pragma unroll
    for (int j = 0; j < 16; ++j) {
        float bj = b2[j * 16 + c0];
#pragma unroll
        for (int r = 0; r < 4; ++r) {
            float v = acc[j][r] + bj;
            if (v > 0.f) {
                int node = s_dst[edg + r];
                atomicMax((int*)&agg[(size_t)node * 256 + j * 16 + c0], __float_as_int(v));
            }
        }
    }
}

// feat[N,288] = [agg | t | a] -> bf16
__global__ void build_feat(const float* __restrict__ agg, const float* __restrict__ t,
                           const float* __restrict__ a, ushort_t* __restrict__ featbf)
{
    int idx = blockIdx.x * 256 + threadIdx.x;
    if (idx >= N_NODES * 288) return;
    int n = idx / 288, c = idx - n * 288;
    float v;
    if (c < 256)      v = agg[(size_t)n * 256 + c];
    else if (c < 272) v = t[n * 16 + (c - 256)];
    else              v = a[n * 16 + (c - 272)];
    featbf[idx] = f2bf(v);
}

// GRU combine (bf16 gates, f32 h): hnew = (1-z)*tanh(i_n + r*h_n) + z*h
__global__ void gru_combine(const ushort_t* __restrict__ gi, const ushort_t* __restrict__ gh,
                            const float* __restrict__ hf,
                            float* __restrict__ hout, ushort_t* __restrict__ hbf)
{
    int idx = blockIdx.x * 256 + threadIdx.x;
    if (idx >= N_NODES * 128) return;
    int n = idx >> 7, c2 = (idx & 127) * 2;
    size_t gb = (size_t)n * 768 + c2;
    uint_t ir = *(const uint_t*)&gi[gb];
    uint_t iz = *(const uint_t*)&gi[gb + 256];
    uint_t in = *(const uint_t*)&gi[gb + 512];
    uint_t hr = *(const uint_t*)&gh[gb];
    uint_t hz = *(const uint_t*)&gh[gb + 256];
    uint_t hn = *(const uint_t*)&gh[gb + 512];
    float2 h = *(const float2*)&hf[(size_t)n * 256 + c2];
    float r0 = 1.f / (1.f + expf(-(bf2f(ir & 0xffffu) + bf2f(hr & 0xffffu))));
    float z0 = 1.f / (1.f + expf(-(bf2f(iz & 0xffffu) + bf2f(hz & 0xffffu))));
    float n0 = tanhf(bf2f(in & 0xffffu) + r0 * bf2f(hn & 0xffffu));
    float v0 = (1.f - z0) * n0 + z0 * h.x;
    float r1 = 1.f / (1.f + expf(-(bf2f(ir >> 16) + bf2f(hr >> 16))));
    float z1 = 1.f / (1.f + expf(-(bf2f(iz >> 16) + bf2f(hz >> 16))));
    float n1 = tanhf(bf2f(in >> 16) + r1 * bf2f(hn >> 16));
    float v1 = (1.f - z1) * n1 + z1 * h.y;
    float2 o; o.x = v0; o.y = v1;
    *(float2*)&hout[(size_t)n * 256 + c2] = o;
    *(uint_t*)&hbf[(size_t)n * 256 + c2] = (uint_t)f2bf(v0) | ((uint_t)f2bf(v1) << 16);
}

// z = mu + eps * exp(0.5*log_var)
__global__ void z_kernel(const float* __restrict__ mu, const float* __restrict__ lv,
                         const float* __restrict__ eps, float* __restrict__ z)
{
    int idx = blockIdx.x * 256 + threadIdx.x;
    if (idx >= N_NODES * 64) return;
    z[idx] = mu[idx] + eps[idx] * expf(0.5f * lv[idx]);
}

extern "C" void kernel_launch(void* const* d_in, const int* in_sizes, int n_in,
                              void* d_out, int out_size, void* d_ws, size_t ws_size,
                              hipStream_t stream)
{
    const float* x      = (const float*)d_in[0];
    const float* t      = (const float*)d_in[1];
    const float* a      = (const float*)d_in[2];
    const float* eps    = (const float*)d_in[3];
    const int*   ei     = (const int*)d_in[4];
    const float* enc_w1 = (const float*)d_in[5];
    const float* enc_b1 = (const float*)d_in[6];
    const float* enc_w2 = (const float*)d_in[7];
    const float* enc_b2 = (const float*)d_in[8];
    const float* hi_w0  = (const float*)d_in[9];
    const float* hi_b0  = (const float*)d_in[10];
    const float* hi_w1  = (const float*)d_in[11];
    const float* hi_b1  = (const float*)d_in[12];
    const float* wih0   = (const float*)d_in[13];
    const float* whh0   = (const float*)d_in[14];
    const float* bih0   = (const float*)d_in[15];
    const float* bhh0   = (const float*)d_in[16];
    const float* wih1   = (const float*)d_in[17];
    const float* whh1   = (const float*)d_in[18];
    const float* bih1   = (const float*)d_in[19];
    const float* bhh1   = (const float*)d_in[20];
    const float* mu_w   = (const float*)d_in[21];
    const float* mu_b   = (const float*)d_in[22];
    const float* lv_w   = (const float*)d_in[23];
    const float* lv_b   = (const float*)d_in[24];

    // workspace (byte offsets; peak 164.5 MB, round-2 layout proved >=187 MB)
    char* W = (char*)d_ws;
    ushort_t* pk     = (ushort_t*)(W + 0);           // packed weights, 4.49MB
    float*    bpq    = (float*)(W + 4489216);
    ushort_t* xbf    = (ushort_t*)(W + 4491264);
    float*    agg    = (float*)(W + 9611264);        // R1: agg -> h0f
    float*    h0f    = (float*)(W + 9611264);
    ushort_t* pqbf   = (ushort_t*)(W + 30091264);    // R2: pqbf -> h1f
    float*    h1f    = (float*)(W + 30091264);
    ushort_t* featbf = (ushort_t*)(W + 50571264);
    ushort_t* h0bf   = (ushort_t*)(W + 62091264);
    ushort_t* h1bf   = (ushort_t*)(W + 72331264);
    ushort_t* g_i    = (ushort_t*)(W + 82571264);
    ushort_t* g_h    = (ushort_t*)(W + 113291264);
    ushort_t* nh0bf  = (ushort_t*)(W + 144011264);
    ushort_t* nh1bf  = (ushort_t*)(W + 154251264);

    float* out_h0 = (float*)d_out;
    float* out_h1 = out_h0 + (size_t)N_NODES * 256;
    float* out_mu = out_h1 + (size_t)N_NODES * 256;
    float* out_lv = out_mu + (size_t)N_NODES * 64;
    float* out_z  = out_lv + (size_t)N_NODES * 64;

    dim3 blk(256);

    pack_all<<<dim3(108, 11), blk, 0, stream>>>(enc_w1, enc_b1, enc_w2, hi_w0, hi_w1,
                                                wih0, whh0, wih1, whh1, mu_w, lv_w, pk, bpq);
    xcvt<<<2500, blk, 0, stream>>>(x, xbf);
    hipMemsetAsync(agg, 0, (size_t)N_NODES * 256 * sizeof(float), stream);

    // PQ = xbf @ WPQ^T + bPQ -> bf16 [N,512]
    mgemm<256, 1><<<dim3(313, 2), blk, 0, stream>>>(xbf, 128, N_NODES, 128,
                                                    pk + 0, 32, bpq, nullptr, pqbf, 512);
    // edge layer2 + segment-max
    edge_mfma<<<5000, blk, 0, stream>>>(pqbf, ei, pk + 65536, enc_b2, agg);

    build_feat<<<22500, blk, 0, stream>>>(agg, t, a, featbf);

    // h0, h1 = tanh(feat @ hi_w^T + b)  (dual f32 + bf16)
    mgemm<256, 2><<<dim3(313, 1), blk, 0, stream>>>(featbf, 288, N_NODES, 288,
                                                    pk + 131072, 16, hi_b0, h0f, h0bf, 256);
    mgemm<256, 2><<<dim3(313, 1), blk, 0, stream>>>(featbf, 288, N_NODES, 288,
                                                    pk + 204800, 16, hi_b1, h1f, h1bf, 256);
    // layer-0 GRU gates
    mgemm<256, 1><<<dim3(313, 3), blk, 0, stream>>>(featbf, 288, N_NODES, 288,
                                                    pk + 278528, 48, bih0, nullptr, g_i, 768);
    mgemm<256, 1><<<dim3(313, 3), blk, 0, stream>>>(h0bf, 256, N_NODES, 256,
                                                    pk + 499712, 48, bhh0, nullptr, g_h, 768);
    gru_combine<<<10000, blk, 0, stream>>>(g_i, g_h, h0f, out_h0, nh0bf);
    // layer-1 GRU gates
    mgemm<256, 1><<<dim3(313, 3), blk, 0, stream>>>(nh0bf, 256, N_NODES, 256,
                                                    pk + 696320, 48, bih1, nullptr, g_i, 768);
    mgemm<256, 1><<<dim3(313, 3), blk, 0, stream>>>(h1bf, 256, N_NODES, 256,
                                                    pk + 892928, 48, bhh1, nullptr, g_h, 768);
    gru_combine<<<10000, blk, 0, stream>>>(g_i, g_h, h1f, out_h1, nh1bf);
    // heads
    mgemm<64, 0><<<dim3(313, 1), blk, 0, stream>>>(nh1bf, 256, N_NODES, 256,
                                                   pk + 1089536, 4, mu_b, out_mu, nullptr, 64);
    mgemm<64, 0><<<dim3(313, 1), blk, 0, stream>>>(nh1bf, 256, N_NODES, 256,
                                                   pk + 1105920, 4, lv_b, out_lv, nullptr, 64);
    z_kernel<<<5000, blk, 0, stream>>>(out_mu, out_lv, eps, out_z);
}

// Round 9
// 752.911 us; speedup vs baseline: 2.3179x; 1.2566x over previous
//
#include <hip/hip_runtime.h>
#include <math.h>

#define N_NODES 20000
#define N_EDGES 320000

typedef __attribute__((ext_vector_type(8))) short bf16x8;
typedef __attribute__((ext_vector_type(4))) float f32x4;
typedef unsigned short ushort_t;
typedef unsigned int uint_t;

__device__ __forceinline__ float bf2f(uint_t u) {
    uint_t i = u << 16; float f; __builtin_memcpy(&f, &i, 4); return f;
}
__device__ __forceinline__ ushort_t f2bf(float f) {
    uint_t i; __builtin_memcpy(&i, &f, 4);
    uint_t r = i + 0x7fffu + ((i >> 16) & 1u);
    return (ushort_t)(r >> 16);
}

// ---------------------------------------------------------------------------
// Pack weights into MFMA fragment order, bf16:
// layout per weight: [k0 = K/32][ot = NO/16][lane = 64][8 bf16]
// lane's 8 elems = W[row = ot*16 + (lane&15)][k = k0*32 + (lane>>4)*8 + j]
// job 0 = WPQ (P/Q transform of enc_w1); job 8 = [muw;lvw]; job 9 = biases
// ---------------------------------------------------------------------------
__global__ void pack_all(const float* __restrict__ w1, const float* __restrict__ b1,
                         const float* __restrict__ w2,
                         const float* __restrict__ hiw0, const float* __restrict__ hiw1,
                         const float* __restrict__ wih0, const float* __restrict__ whh0,
                         const float* __restrict__ wih1, const float* __restrict__ whh1,
                         const float* __restrict__ muw, const float* __restrict__ lvw,
                         const float* __restrict__ mub, const float* __restrict__ lvb,
                         ushort_t* __restrict__ pk, float* __restrict__ bpq)
{
    const int w = blockIdx.y;
    const int i = blockIdx.x * 256 + threadIdx.x;
    if (w == 9) {
        if (i < 256)      bpq[i] = b1[i];
        else if (i < 512) bpq[i] = 0.0f;
        else if (i < 576) bpq[i] = mub[i - 512];
        else if (i < 640) bpq[i] = lvb[i - 576];
        return;
    }
    const int Ks[9]  = {128, 256, 288, 288, 288, 256, 256, 256, 256};
    const int NOs[9] = {512, 256, 256, 256, 768, 768, 768, 768, 128};
    const int DST[9] = {0, 65536, 131072, 204800, 278528, 499712, 696320, 892928, 1089536};
    const float* srcs[9] = {w1, w2, hiw0, hiw1, wih0, whh0, wih1, whh1, muw};
    const int K = Ks[w], NO = NOs[w];
    if (i >= (K * NO) >> 3) return;
    const int lane = i & 63, rest = i >> 6, NOT = NO >> 4;
    const int ot = rest % NOT, k0 = rest / NOT;
    const int row = ot * 16 + (lane & 15);
    const int kb = k0 * 32 + (lane >> 4) * 8;
    ushort_t o[8];
    if (w == 0) {
#pragma unroll
        for (int j = 0; j < 8; ++j) {
            int k = kb + j;
            float v = (row < 256) ? (w1[row * 256 + k] - w1[row * 256 + 128 + k])
                                  : w1[(row - 256) * 256 + 128 + k];
            o[j] = f2bf(v);
        }
    } else if (w == 8) {
#pragma unroll
        for (int j = 0; j < 8; ++j) {
            float v = (row < 64) ? muw[row * 256 + kb + j] : lvw[(row - 64) * 256 + kb + j];
            o[j] = f2bf(v);
        }
    } else {
        const float* s = srcs[w];
#pragma unroll
        for (int j = 0; j < 8; ++j) o[j] = f2bf(s[(size_t)row * K + kb + j]);
    }
    ushort_t* d = pk + DST[w] + (size_t)i * 8;
    ((uint_t*)d)[0] = (uint_t)o[0] | ((uint_t)o[1] << 16);
    ((uint_t*)d)[1] = (uint_t)o[2] | ((uint_t)o[3] << 16);
    ((uint_t*)d)[2] = (uint_t)o[4] | ((uint_t)o[5] << 16);
    ((uint_t*)d)[3] = (uint_t)o[6] | ((uint_t)o[7] << 16);
}

// x f32 -> bf16
__global__ void xcvt(const float* __restrict__ x, ushort_t* __restrict__ xbf)
{
    int base = (blockIdx.x * 256 + threadIdx.x) * 4;
    if (base >= N_NODES * 128) return;
    float4 v = *(const float4*)&x[base];
    uint2 u;
    u.x = (uint_t)f2bf(v.x) | ((uint_t)f2bf(v.y) << 16);
    u.y = (uint_t)f2bf(v.z) | ((uint_t)f2bf(v.w) << 16);
    *(uint2*)&xbf[base] = u;
}

// ---------------------------------------------------------------------------
// MFMA GEMM: C = act(Abf[M,K] @ W^T + bias).  BM=64, BN in {64,128},
// 256 thr / 4 waves.  A staged in LDS (XOR swizzle (row&7)<<4).
// OMODE: 0=f32, 1=bf16, 2=dual f32+bf16 with tanh, 3=two-head f32 (mu|lv)
// ---------------------------------------------------------------------------
template <int BN, int OMODE>
__global__ __launch_bounds__(256) void mgemm(
    const ushort_t* __restrict__ Abf, int lda, int M, int K,
    const ushort_t* __restrict__ Wp, int NOtot, const float* __restrict__ bias,
    float* __restrict__ Cf, ushort_t* __restrict__ Cbf, int ldc)
{
    __shared__ char smem[40960];
    const int tid = threadIdx.x;
    const int l = tid & 63, wid = tid >> 6;
    const int m0 = blockIdx.x * 64;
    const int n0 = blockIdx.y * BN;
    const int RS = (K * 2 + 127) & ~127;
    const int CHR = K >> 3;
    for (int c = tid; c < 64 * CHR; c += 256) {
        int row = c / CHR, cb = c - row * CHR;
        int gr = m0 + row; if (gr >= M) gr = M - 1;
        bf16x8 v = *(const bf16x8*)&Abf[(size_t)gr * lda + cb * 8];
        *(bf16x8*)&smem[row * RS + ((cb * 16) ^ ((row & 7) << 4))] = v;
    }
    __syncthreads();

    constexpr int NT = BN / 16;
    f32x4 acc[NT];
#pragma unroll
    for (int j = 0; j < NT; ++j) acc[j] = (f32x4){0.f, 0.f, 0.f, 0.f};
    const int rw = wid * 16 + (l & 15);
    const int hi = l >> 4;
    const int swz = (rw & 7) << 4;
    const int KB = K >> 5;
    const int otb = n0 >> 4;
    for (int k0 = 0; k0 < KB; ++k0) {
        bf16x8 a = *(const bf16x8*)&smem[rw * RS + ((k0 * 64 + hi * 16) ^ swz)];
        const ushort_t* wb = Wp + ((size_t)(k0 * NOtot + otb) * 64 + l) * 8;
#pragma unroll
        for (int j = 0; j < NT; ++j) {
            bf16x8 b = *(const bf16x8*)&wb[(size_t)j * 512];
            acc[j] = __builtin_amdgcn_mfma_f32_16x16x32_bf16(a, b, acc[j], 0, 0, 0);
        }
    }
    const int c0 = l & 15;
    const int r0 = m0 + wid * 16 + hi * 4;
#pragma unroll
    for (int j = 0; j < NT; ++j) {
        float bj = bias[n0 + j * 16 + c0];
#pragma unroll
        for (int r = 0; r < 4; ++r) {
            int gr = r0 + r;
            if (gr >= M) continue;
            float v = acc[j][r] + bj;
            if (OMODE == 2) v = tanhf(v);
            if (OMODE == 3) {
                int col = n0 + j * 16 + c0;
                size_t o = (size_t)gr * 64 + (col & 63) + ((col >= 64) ? (size_t)M * 64 : 0);
                Cf[o] = v;
            } else {
                size_t o = (size_t)gr * ldc + n0 + j * 16 + c0;
                if (OMODE == 0) Cf[o] = v;
                else if (OMODE == 1) Cbf[o] = f2bf(v);
                else { Cf[o] = v; Cbf[o] = f2bf(v); }
            }
        }
    }
}

// ---------------------------------------------------------------------------
// Edge kernel: 64 edges/block, MFMA layer-2,
// relu + segment-max via int atomicMax on non-negative floats.
// Gather phase: one wave per edge, uint2 (8B) loads = 4 channels/lane.
// ---------------------------------------------------------------------------
__global__ __launch_bounds__(256) void edge_mfma(
    const ushort_t* __restrict__ PQbf,
    const int* __restrict__ ei,
    const ushort_t* __restrict__ W2p,
    const float* __restrict__ b2,
    float* __restrict__ agg)
{
    __shared__ char h1s[32768];
    __shared__ int s_dst[64], s_src[64];
    const int tid = threadIdx.x;
    const int e0 = blockIdx.x * 64;
    if (tid < 64) {
        int d = ei[N_EDGES + e0 + tid];
        s_dst[tid] = min(max(d, 0), N_NODES - 1);
    } else if (tid < 128) {
        int s = ei[e0 + tid - 64];
        s_src[tid - 64] = min(max(s, 0), N_NODES - 1);
    }
    __syncthreads();

    const int wv = tid >> 6;       // wave id: handles edges wv, wv+4, ...
    const int ln = tid & 63;       // lane: channels ln*4 .. ln*4+3
#pragma unroll 4
    for (int eb = wv; eb < 64; eb += 4) {
        int dst = s_dst[eb], src = s_src[eb];
        uint2 pu = *(const uint2*)&PQbf[(size_t)dst * 512 + ln * 4];
        uint2 qu = *(const uint2*)&PQbf[(size_t)src * 512 + 256 + ln * 4];
        float v0 = fmaxf(bf2f(pu.x & 0xffffu) + bf2f(qu.x & 0xffffu), 0.f);
        float v1 = fmaxf(bf2f(pu.x >> 16)     + bf2f(qu.x >> 16),     0.f);
        float v2 = fmaxf(bf2f(pu.y & 0xffffu) + bf2f(qu.y & 0xffffu), 0.f);
        float v3 = fmaxf(bf2f(pu.y >> 16)     + bf2f(qu.y >> 16),     0.f);
        uint2 hv;
        hv.x = (uint_t)f2bf(v0) | ((uint_t)f2bf(v1) << 16);
        hv.y = (uint_t)f2bf(v2) | ((uint_t)f2bf(v3) << 16);
        *(uint2*)&h1s[eb * 512 + ((ln * 8) ^ ((eb & 7) << 4))] = hv;
    }
    __syncthreads();

    const int l = tid & 63, wid = tid >> 6;
    const int rw = wid * 16 + (l & 15);
    const int hi = l >> 4;
    const int swz = (rw & 7) << 4;
    f32x4 acc[16];
#pragma unroll
    for (int j = 0; j < 16; ++j) acc[j] = (f32x4){0.f, 0.f, 0.f, 0.f};
    for (int k0 = 0; k0 < 8; ++k0) {
        bf16x8 a = *(const bf16x8*)&h1s[rw * 512 + ((k0 * 64 + hi * 16) ^ swz)];
        const ushort_t* wb = W2p + ((size_t)(k0 * 16) * 64 + l) * 8;
#pragma unroll
        for (int j = 0; j < 16; ++j) {
            bf16x8 b = *(const bf16x8*)&wb[(size_t)j * 512];
            acc[j] = __builtin_amdgcn_mfma_f32_16x16x32_bf16(a, b, acc[j], 0, 0, 0);
        }
    }
    const int c0 = l & 15;
    const int edg = wid * 16 + hi * 4;
#pragma unroll
    for (int j = 0; j < 16; ++j) {
        float bj = b2[j * 16 + c0];
#pragma unroll
        for (int r = 0; r < 4; ++r) {
            float v = acc[j][r] + bj;
            if (v > 0.f) {
                int node = s_dst[edg + r];
                atomicMax((int*)&agg[(size_t)node * 256 + j * 16 + c0], __float_as_int(v));
            }
        }
    }
}

// feat[N,288] = [agg | t | a] -> bf16
__global__ void build_feat(const float* __restrict__ agg, const float* __restrict__ t,
                           const float* __restrict__ a, ushort_t* __restrict__ featbf)
{
    int idx = blockIdx.x * 256 + threadIdx.x;
    if (idx >= N_NODES * 288) return;
    int n = idx / 288, c = idx - n * 288;
    float v;
    if (c < 256)      v = agg[(size_t)n * 256 + c];
    else if (c < 272) v = t[n * 16 + (c - 256)];
    else              v = a[n * 16 + (c - 272)];
    featbf[idx] = f2bf(v);
}

// ---------------------------------------------------------------------------
// Fused GRU layer: gi = A1 @ wih^T, gh = A2 @ whh^T, then full GRU combine.
// Block = 64 rows x 64 gate-channels. Wp layout identical to mgemm packing
// with NOtot=48 (gates stacked r|z|n in the 768-row dimension).
// ---------------------------------------------------------------------------
__global__ __launch_bounds__(256) void gru_fused(
    const ushort_t* __restrict__ A1, int K1,
    const ushort_t* __restrict__ A2,              // [N,256]
    const ushort_t* __restrict__ Wp1,
    const ushort_t* __restrict__ Wp2,
    const float* __restrict__ bih, const float* __restrict__ bhh,
    const float* __restrict__ hf,                 // [N,256] f32
    float* __restrict__ houtf,
    ushort_t* __restrict__ houtb)
{
    __shared__ char smem[40960];
    const int tid = threadIdx.x;
    const int l = tid & 63, wid = tid >> 6;
    const int m0 = blockIdx.x * 64;
    const int n0 = blockIdx.y * 64;
    const int rw = wid * 16 + (l & 15);
    const int hi = l >> 4;
    const int swz = (rw & 7) << 4;
    const int otb = n0 >> 4;

    f32x4 aR[4], aZ[4], aN[4], bR[4], bZ[4], bN[4];
#pragma unroll
    for (int j = 0; j < 4; ++j) {
        aR[j] = (f32x4){0.f,0.f,0.f,0.f}; aZ[j] = aR[j]; aN[j] = aR[j];
        bR[j] = aR[j]; bZ[j] = aR[j]; bN[j] = aR[j];
    }

    // ---- stage A1, K-loop 1 (input gates)
    {
        const int RS = (K1 * 2 + 127) & ~127;
        const int CHR = K1 >> 3;
        for (int c = tid; c < 64 * CHR; c += 256) {
            int row = c / CHR, cb = c - row * CHR;
            int gr = m0 + row; if (gr >= N_NODES) gr = N_NODES - 1;
            bf16x8 v = *(const bf16x8*)&A1[(size_t)gr * K1 + cb * 8];
            *(bf16x8*)&smem[row * RS + ((cb * 16) ^ ((row & 7) << 4))] = v;
        }
        __syncthreads();
        const int KB = K1 >> 5;
        for (int k0 = 0; k0 < KB; ++k0) {
            bf16x8 a = *(const bf16x8*)&smem[rw * RS + ((k0 * 64 + hi * 16) ^ swz)];
            const ushort_t* wb = Wp1 + ((size_t)(k0 * 48) * 64 + l) * 8;
#pragma unroll
            for (int j = 0; j < 4; ++j) {
                bf16x8 b0 = *(const bf16x8*)&wb[(size_t)(otb + j) * 512];
                aR[j] = __builtin_amdgcn_mfma_f32_16x16x32_bf16(a, b0, aR[j], 0, 0, 0);
                bf16x8 b1 = *(const bf16x8*)&wb[(size_t)(16 + otb + j) * 512];
                aZ[j] = __builtin_amdgcn_mfma_f32_16x16x32_bf16(a, b1, aZ[j], 0, 0, 0);
                bf16x8 b2 = *(const bf16x8*)&wb[(size_t)(32 + otb + j) * 512];
                aN[j] = __builtin_amdgcn_mfma_f32_16x16x32_bf16(a, b2, aN[j], 0, 0, 0);
            }
        }
    }
    __syncthreads();
    // ---- stage A2 (K=256), K-loop 2 (hidden gates)
    {
        for (int c = tid; c < 64 * 32; c += 256) {
            int row = c >> 5, cb = c & 31;
            int gr = m0 + row; if (gr >= N_NODES) gr = N_NODES - 1;
            bf16x8 v = *(const bf16x8*)&A2[(size_t)gr * 256 + cb * 8];
            *(bf16x8*)&smem[row * 512 + ((cb * 16) ^ ((row & 7) << 4))] = v;
        }
        __syncthreads();
        for (int k0 = 0; k0 < 8; ++k0) {
            bf16x8 a = *(const bf16x8*)&smem[rw * 512 + ((k0 * 64 + hi * 16) ^ swz)];
            const ushort_t* wb = Wp2 + ((size_t)(k0 * 48) * 64 + l) * 8;
#pragma unroll
            for (int j = 0; j < 4; ++j) {
                bf16x8 b0 = *(const bf16x8*)&wb[(size_t)(otb + j) * 512];
                bR[j] = __builtin_amdgcn_mfma_f32_16x16x32_bf16(a, b0, bR[j], 0, 0, 0);
                bf16x8 b1 = *(const bf16x8*)&wb[(size_t)(16 + otb + j) * 512];
                bZ[j] = __builtin_amdgcn_mfma_f32_16x16x32_bf16(a, b1, bZ[j], 0, 0, 0);
                bf16x8 b2 = *(const bf16x8*)&wb[(size_t)(32 + otb + j) * 512];
                bN[j] = __builtin_amdgcn_mfma_f32_16x16x32_bf16(a, b2, bN[j], 0, 0, 0);
            }
        }
    }
    // ---- GRU combine epilogue
    const int c0 = l & 15;
    const int r0 = m0 + wid * 16 + hi * 4;
#pragma unroll
    for (int j = 0; j < 4; ++j) {
        int col = n0 + j * 16 + c0;
        float br_ = bih[col], bz_ = bih[256 + col], bn_ = bih[512 + col];
        float cr_ = bhh[col], cz_ = bhh[256 + col], cn_ = bhh[512 + col];
#pragma unroll
        for (int r = 0; r < 4; ++r) {
            int gr = r0 + r;
            if (gr >= N_NODES) continue;
            float ir = aR[j][r] + br_, iz = aZ[j][r] + bz_, in_ = aN[j][r] + bn_;
            float hr = bR[j][r] + cr_, hz = bZ[j][r] + cz_, hn = bN[j][r] + cn_;
            float h = hf[(size_t)gr * 256 + col];
            float rg = 1.f / (1.f + expf(-(ir + hr)));
            float zg = 1.f / (1.f + expf(-(iz + hz)));
            float ng = tanhf(in_ + rg * hn);
            float v = (1.f - zg) * ng + zg * h;
            houtf[(size_t)gr * 256 + col] = v;
            houtb[(size_t)gr * 256 + col] = f2bf(v);
        }
    }
}

// z = mu + eps * exp(0.5*log_var)
__global__ void z_kernel(const float* __restrict__ mu, const float* __restrict__ lv,
                         const float* __restrict__ eps, float* __restrict__ z)
{
    int idx = blockIdx.x * 256 + threadIdx.x;
    if (idx >= N_NODES * 64) return;
    z[idx] = mu[idx] + eps[idx] * expf(0.5f * lv[idx]);
}

extern "C" void kernel_launch(void* const* d_in, const int* in_sizes, int n_in,
                              void* d_out, int out_size, void* d_ws, size_t ws_size,
                              hipStream_t stream)
{
    const float* x      = (const float*)d_in[0];
    const float* t      = (const float*)d_in[1];
    const float* a      = (const float*)d_in[2];
    const float* eps    = (const float*)d_in[3];
    const int*   ei     = (const int*)d_in[4];
    const float* enc_w1 = (const float*)d_in[5];
    const float* enc_b1 = (const float*)d_in[6];
    const float* enc_w2 = (const float*)d_in[7];
    const float* enc_b2 = (const float*)d_in[8];
    const float* hi_w0  = (const float*)d_in[9];
    const float* hi_b0  = (const float*)d_in[10];
    const float* hi_w1  = (const float*)d_in[11];
    const float* hi_b1  = (const float*)d_in[12];
    const float* wih0   = (const float*)d_in[13];
    const float* whh0   = (const float*)d_in[14];
    const float* bih0   = (const float*)d_in[15];
    const float* bhh0   = (const float*)d_in[16];
    const float* wih1   = (const float*)d_in[17];
    const float* whh1   = (const float*)d_in[18];
    const float* bih1   = (const float*)d_in[19];
    const float* bhh1   = (const float*)d_in[20];
    const float* mu_w   = (const float*)d_in[21];
    const float* mu_b   = (const float*)d_in[22];
    const float* lv_w   = (const float*)d_in[23];
    const float* lv_b   = (const float*)d_in[24];

    // workspace layout (bytes), peak ~100.8 MB
    char* W = (char*)d_ws;
    ushort_t* pk     = (ushort_t*)(W + 0);           // 2,244,608 B packed weights
    float*    bpq    = (float*)(W + 2244608);        // 640 floats (bPQ | headbias)
    ushort_t* xbf    = (ushort_t*)(W + 2247680);     // 5,120,000
    float*    agg    = (float*)(W + 7368704);        // 20,480,000 (-> h0f)
    float*    h0f    = (float*)(W + 7368704);
    ushort_t* pqbf   = (ushort_t*)(W + 27848704);    // 20,480,000 (-> h1f)
    float*    h1f    = (float*)(W + 27848704);
    ushort_t* featbf = (ushort_t*)(W + 48328704);    // 11,520,000
    ushort_t* h0bf   = (ushort_t*)(W + 59848704);    // 10,240,000
    ushort_t* h1bf   = (ushort_t*)(W + 70088704);    // 10,240,000
    ushort_t* nh0bf  = (ushort_t*)(W + 80328704);    // 10,240,000
    ushort_t* nh1bf  = (ushort_t*)(W + 90568704);    // 10,240,000

    float* out_h0 = (float*)d_out;
    float* out_h1 = out_h0 + (size_t)N_NODES * 256;
    float* out_mu = out_h1 + (size_t)N_NODES * 256;
    float* out_lv = out_mu + (size_t)N_NODES * 64;
    float* out_z  = out_lv + (size_t)N_NODES * 64;

    dim3 blk(256);

    pack_all<<<dim3(108, 10), blk, 0, stream>>>(enc_w1, enc_b1, enc_w2, hi_w0, hi_w1,
                                                wih0, whh0, wih1, whh1, mu_w, lv_w,
                                                mu_b, lv_b, pk, bpq);
    xcvt<<<2500, blk, 0, stream>>>(x, xbf);
    hipMemsetAsync(agg, 0, (size_t)N_NODES * 256 * sizeof(float), stream);

    // PQ = xbf @ WPQ^T + bPQ -> bf16 [N,512]
    mgemm<128, 1><<<dim3(313, 4), blk, 0, stream>>>(xbf, 128, N_NODES, 128,
                                                    pk + 0, 32, bpq, nullptr, pqbf, 512);
    // edge layer2 + segment-max
    edge_mfma<<<5000, blk, 0, stream>>>(pqbf, ei, pk + 65536, enc_b2, agg);

    build_feat<<<22500, blk, 0, stream>>>(agg, t, a, featbf);

    // h0, h1 = tanh(feat @ hi_w^T + b)  (dual f32 + bf16)
    mgemm<128, 2><<<dim3(313, 2), blk, 0, stream>>>(featbf, 288, N_NODES, 288,
                                                    pk + 131072, 16, hi_b0, h0f, h0bf, 256);
    mgemm<128, 2><<<dim3(313, 2), blk, 0, stream>>>(featbf, 288, N_NODES, 288,
                                                    pk + 204800, 16, hi_b1, h1f, h1bf, 256);
    // fused GRU layers
    gru_fused<<<dim3(313, 4), blk, 0, stream>>>(featbf, 288, h0bf,
                                                pk + 278528, pk + 499712,
                                                bih0, bhh0, h0f, out_h0, nh0bf);
    gru_fused<<<dim3(313, 4), blk, 0, stream>>>(nh0bf, 256, h1bf,
                                                pk + 696320, pk + 892928,
                                                bih1, bhh1, h1f, out_h1, nh1bf);
    // fused heads: [mu | lv]
    mgemm<64, 3><<<dim3(313, 2), blk, 0, stream>>>(nh1bf, 256, N_NODES, 256,
                                                   pk + 1089536, 8, bpq + 512,
                                                   out_mu, nullptr, 64);
    z_kernel<<<5000, blk, 0, stream>>>(out_mu, out_lv, eps, out_z);
}

// Round 11
// 701.149 us; speedup vs baseline: 2.4890x; 1.0738x over previous
//
#include <hip/hip_runtime.h>
#include <math.h>

#define N_NODES 20000
#define N_EDGES 320000

typedef __attribute__((ext_vector_type(8))) short bf16x8;
typedef __attribute__((ext_vector_type(4))) float f32x4;
typedef unsigned short ushort_t;
typedef unsigned int uint_t;

__device__ __forceinline__ float bf2f(uint_t u) {
    uint_t i = u << 16; float f; __builtin_memcpy(&f, &i, 4); return f;
}
__device__ __forceinline__ ushort_t f2bf(float f) {
    uint_t i; __builtin_memcpy(&i, &f, 4);
    uint_t r = i + 0x7fffu + ((i >> 16) & 1u);
    return (ushort_t)(r >> 16);
}

// ---------------------------------------------------------------------------
// Pack weights into MFMA fragment order, bf16:
// layout per weight: [k0 = K/32][ot = NO/16][lane = 64][8 bf16]
// lane's 8 elems = W[row = ot*16 + (lane&15)][k = k0*32 + (lane>>4)*8 + j]
// job 0 = WPQ (P/Q transform of enc_w1); job 8 = [muw;lvw]; job 9 = biases
// ---------------------------------------------------------------------------
__global__ void pack_all(const float* __restrict__ w1, const float* __restrict__ b1,
                         const float* __restrict__ w2,
                         const float* __restrict__ hiw0, const float* __restrict__ hiw1,
                         const float* __restrict__ wih0, const float* __restrict__ whh0,
                         const float* __restrict__ wih1, const float* __restrict__ whh1,
                         const float* __restrict__ muw, const float* __restrict__ lvw,
                         const float* __restrict__ mub, const float* __restrict__ lvb,
                         ushort_t* __restrict__ pk, float* __restrict__ bpq)
{
    const int w = blockIdx.y;
    const int i = blockIdx.x * 256 + threadIdx.x;
    if (w == 9) {
        if (i < 256)      bpq[i] = b1[i];
        else if (i < 512) bpq[i] = 0.0f;
        else if (i < 576) bpq[i] = mub[i - 512];
        else if (i < 640) bpq[i] = lvb[i - 576];
        return;
    }
    const int Ks[9]  = {128, 256, 288, 288, 288, 256, 256, 256, 256};
    const int NOs[9] = {512, 256, 256, 256, 768, 768, 768, 768, 128};
    const int DST[9] = {0, 65536, 131072, 204800, 278528, 499712, 696320, 892928, 1089536};
    const float* srcs[9] = {w1, w2, hiw0, hiw1, wih0, whh0, wih1, whh1, muw};
    const int K = Ks[w], NO = NOs[w];
    if (i >= (K * NO) >> 3) return;
    const int lane = i & 63, rest = i >> 6, NOT = NO >> 4;
    const int ot = rest % NOT, k0 = rest / NOT;
    const int row = ot * 16 + (lane & 15);
    const int kb = k0 * 32 + (lane >> 4) * 8;
    ushort_t o[8];
    if (w == 0) {
#pragma unroll
        for (int j = 0; j < 8; ++j) {
            int k = kb + j;
            float v = (row < 256) ? (w1[row * 256 + k] - w1[row * 256 + 128 + k])
                                  : w1[(row - 256) * 256 + 128 + k];
            o[j] = f2bf(v);
        }
    } else if (w == 8) {
#pragma unroll
        for (int j = 0; j < 8; ++j) {
            float v = (row < 64) ? muw[row * 256 + kb + j] : lvw[(row - 64) * 256 + kb + j];
            o[j] = f2bf(v);
        }
    } else {
        const float* s = srcs[w];
#pragma unroll
        for (int j = 0; j < 8; ++j) o[j] = f2bf(s[(size_t)row * K + kb + j]);
    }
    ushort_t* d = pk + DST[w] + (size_t)i * 8;
    ((uint_t*)d)[0] = (uint_t)o[0] | ((uint_t)o[1] << 16);
    ((uint_t*)d)[1] = (uint_t)o[2] | ((uint_t)o[3] << 16);
    ((uint_t*)d)[2] = (uint_t)o[4] | ((uint_t)o[5] << 16);
    ((uint_t*)d)[3] = (uint_t)o[6] | ((uint_t)o[7] << 16);
}

// x f32 -> bf16
__global__ void xcvt(const float* __restrict__ x, ushort_t* __restrict__ xbf)
{
    int base = (blockIdx.x * 256 + threadIdx.x) * 4;
    if (base >= N_NODES * 128) return;
    float4 v = *(const float4*)&x[base];
    uint2 u;
    u.x = (uint_t)f2bf(v.x) | ((uint_t)f2bf(v.y) << 16);
    u.y = (uint_t)f2bf(v.z) | ((uint_t)f2bf(v.w) << 16);
    *(uint2*)&xbf[base] = u;
}

// ---------------------------------------------------------------------------
// MFMA GEMM: C = act(Abf[M,K] @ W^T + bias).  BM=64, BN in {64,128},
// 256 thr / 4 waves.  A staged in LDS (XOR swizzle (row&7)<<4).
// OMODE: 0=f32, 1=bf16, 2=dual f32+bf16 with tanh, 3=two-head f32 (mu|lv)
// ---------------------------------------------------------------------------
template <int BN, int OMODE>
__global__ __launch_bounds__(256) void mgemm(
    const ushort_t* __restrict__ Abf, int lda, int M, int K,
    const ushort_t* __restrict__ Wp, int NOtot, const float* __restrict__ bias,
    float* __restrict__ Cf, ushort_t* __restrict__ Cbf, int ldc)
{
    __shared__ char smem[40960];
    const int tid = threadIdx.x;
    const int l = tid & 63, wid = tid >> 6;
    const int m0 = blockIdx.x * 64;
    const int n0 = blockIdx.y * BN;
    const int RS = (K * 2 + 127) & ~127;
    const int CHR = K >> 3;
    for (int c = tid; c < 64 * CHR; c += 256) {
        int row = c / CHR, cb = c - row * CHR;
        int gr = m0 + row; if (gr >= M) gr = M - 1;
        bf16x8 v = *(const bf16x8*)&Abf[(size_t)gr * lda + cb * 8];
        *(bf16x8*)&smem[row * RS + ((cb * 16) ^ ((row & 7) << 4))] = v;
    }
    __syncthreads();

    constexpr int NT = BN / 16;
    f32x4 acc[NT];
#pragma unroll
    for (int j = 0; j < NT; ++j) acc[j] = (f32x4){0.f, 0.f, 0.f, 0.f};
    const int rw = wid * 16 + (l & 15);
    const int hi = l >> 4;
    const int swz = (rw & 7) << 4;
    const int KB = K >> 5;
    const int otb = n0 >> 4;
    for (int k0 = 0; k0 < KB; ++k0) {
        bf16x8 a = *(const bf16x8*)&smem[rw * RS + ((k0 * 64 + hi * 16) ^ swz)];
        const ushort_t* wb = Wp + ((size_t)(k0 * NOtot + otb) * 64 + l) * 8;
#pragma unroll
        for (int j = 0; j < NT; ++j) {
            bf16x8 b = *(const bf16x8*)&wb[(size_t)j * 512];
            acc[j] = __builtin_amdgcn_mfma_f32_16x16x32_bf16(a, b, acc[j], 0, 0, 0);
        }
    }
    const int c0 = l & 15;
    const int r0 = m0 + wid * 16 + hi * 4;
#pragma unroll
    for (int j = 0; j < NT; ++j) {
        float bj = bias[n0 + j * 16 + c0];
#pragma unroll
        for (int r = 0; r < 4; ++r) {
            int gr = r0 + r;
            if (gr >= M) continue;
            float v = acc[j][r] + bj;
            if (OMODE == 2) v = tanhf(v);
            if (OMODE == 3) {
                int col = n0 + j * 16 + c0;
                size_t o = (size_t)gr * 64 + (col & 63) + ((col >= 64) ? (size_t)M * 64 : 0);
                Cf[o] = v;
            } else {
                size_t o = (size_t)gr * ldc + n0 + j * 16 + c0;
                if (OMODE == 0) Cf[o] = v;
                else if (OMODE == 1) Cbf[o] = f2bf(v);
                else { Cf[o] = v; Cbf[o] = f2bf(v); }
            }
        }
    }
}

// ---------------------------------------------------------------------------
// Edge kernel: 32 edges/block (16.6 KB LDS -> 8 blocks/CU for latency hiding
// of the random PQ gather).  MFMA layer-2: wave = 16 edges x 128 cols.
// relu + segment-max via int atomicMax on non-negative floats (fire-forget).
// ---------------------------------------------------------------------------
__global__ __launch_bounds__(256) void edge_mfma(
    const ushort_t* __restrict__ PQbf,
    const int* __restrict__ ei,
    const ushort_t* __restrict__ W2p,
    const float* __restrict__ b2,
    float* __restrict__ agg)
{
    __shared__ char h1s[16384];           // 32 x 512B
    __shared__ int s_dst[32], s_src[32];
    const int tid = threadIdx.x;
    const int e0 = blockIdx.x * 32;
    if (tid < 32) {
        int d = ei[N_EDGES + e0 + tid];
        s_dst[tid] = min(max(d, 0), N_NODES - 1);
    } else if (tid < 64) {
        int s = ei[e0 + tid - 32];
        s_src[tid - 32] = min(max(s, 0), N_NODES - 1);
    }
    __syncthreads();

    const int wv = tid >> 6;       // wave id: edges wv, wv+4, ...
    const int ln = tid & 63;       // lane: channels ln*4 .. ln*4+3
#pragma unroll 4
    for (int eb = wv; eb < 32; eb += 4) {
        int dst = s_dst[eb], src = s_src[eb];
        uint2 pu = *(const uint2*)&PQbf[(size_t)dst * 512 + ln * 4];
        uint2 qu = *(const uint2*)&PQbf[(size_t)src * 512 + 256 + ln * 4];
        float v0 = fmaxf(bf2f(pu.x & 0xffffu) + bf2f(qu.x & 0xffffu), 0.f);
        float v1 = fmaxf(bf2f(pu.x >> 16)     + bf2f(qu.x >> 16),     0.f);
        float v2 = fmaxf(bf2f(pu.y & 0xffffu) + bf2f(qu.y & 0xffffu), 0.f);
        float v3 = fmaxf(bf2f(pu.y >> 16)     + bf2f(qu.y >> 16),     0.f);
        uint2 hv;
        hv.x = (uint_t)f2bf(v0) | ((uint_t)f2bf(v1) << 16);
        hv.y = (uint_t)f2bf(v2) | ((uint_t)f2bf(v3) << 16);
        *(uint2*)&h1s[eb * 512 + ((ln * 8) ^ ((eb & 7) << 4))] = hv;
    }
    __syncthreads();

    // wave -> (row-tile, col-half): rows (wid&1)*16..+15, cols (wid>>1)*128..+127
    const int l = tid & 63, wid = tid >> 6;
    const int rw = (wid & 1) * 16 + (l & 15);
    const int hi = l >> 4;
    const int swz = (rw & 7) << 4;
    const int otb = (wid >> 1) * 8;       // first 16-col tile index of this wave
    f32x4 acc[8];
#pragma unroll
    for (int j = 0; j < 8; ++j) acc[j] = (f32x4){0.f, 0.f, 0.f, 0.f};
    for (int k0 = 0; k0 < 8; ++k0) {
        bf16x8 a = *(const bf16x8*)&h1s[rw * 512 + ((k0 * 64 + hi * 16) ^ swz)];
        const ushort_t* wb = W2p + ((size_t)(k0 * 16 + otb) * 64 + l) * 8;
#pragma unroll
        for (int j = 0; j < 8; ++j) {
            bf16x8 b = *(const bf16x8*)&wb[(size_t)j * 512];
            acc[j] = __builtin_amdgcn_mfma_f32_16x16x32_bf16(a, b, acc[j], 0, 0, 0);
        }
    }
    const int c0 = l & 15;
    const int edg = (wid & 1) * 16 + hi * 4;
#pragma unroll
    for (int j = 0; j < 8; ++j) {
        int col = (otb + j) * 16 + c0;
        float bj = b2[col];
#pragma unroll
        for (int r = 0; r < 4; ++r) {
            float v = acc[j][r] + bj;
            if (v > 0.f) {
                int node = s_dst[edg + r];
                atomicMax((int*)&agg[(size_t)node * 256 + col], __float_as_int(v));
            }
        }
    }
}

// feat[N,288] = [agg | t | a] -> bf16
__global__ void build_feat(const float* __restrict__ agg, const float* __restrict__ t,
                           const float* __restrict__ a, ushort_t* __restrict__ featbf)
{
    int idx = blockIdx.x * 256 + threadIdx.x;
    if (idx >= N_NODES * 288) return;
    int n = idx / 288, c = idx - n * 288;
    float v;
    if (c < 256)      v = agg[(size_t)n * 256 + c];
    else if (c < 272) v = t[n * 16 + (c - 256)];
    else              v = a[n * 16 + (c - 272)];
    featbf[idx] = f2bf(v);
}

// ---------------------------------------------------------------------------
// Fused GRU layer: gi = A1 @ wih^T, gh = A2 @ whh^T, then full GRU combine.
// Block = 64 rows x 64 gate-channels. Wp layout identical to mgemm packing
// with NOtot=48 (gates stacked r|z|n in the 768-row dimension).
// ---------------------------------------------------------------------------
__global__ __launch_bounds__(256) void gru_fused(
    const ushort_t* __restrict__ A1, int K1,
    const ushort_t* __restrict__ A2,              // [N,256]
    const ushort_t* __restrict__ Wp1,
    const ushort_t* __restrict__ Wp2,
    const float* __restrict__ bih, const float* __restrict__ bhh,
    const float* __restrict__ hf,                 // [N,256] f32
    float* __restrict__ houtf,
    ushort_t* __restrict__ houtb)
{
    __shared__ char smem[40960];
    const int tid = threadIdx.x;
    const int l = tid & 63, wid = tid >> 6;
    const int m0 = blockIdx.x * 64;
    const int n0 = blockIdx.y * 64;
    const int rw = wid * 16 + (l & 15);
    const int hi = l >> 4;
    const int swz = (rw & 7) << 4;
    const int otb = n0 >> 4;

    f32x4 aR[4], aZ[4], aN[4], bR[4], bZ[4], bN[4];
#pragma unroll
    for (int j = 0; j < 4; ++j) {
        aR[j] = (f32x4){0.f,0.f,0.f,0.f}; aZ[j] = aR[j]; aN[j] = aR[j];
        bR[j] = aR[j]; bZ[j] = aR[j]; bN[j] = aR[j];
    }

    // ---- stage A1, K-loop 1 (input gates)
    {
        const int RS = (K1 * 2 + 127) & ~127;
        const int CHR = K1 >> 3;
        for (int c = tid; c < 64 * CHR; c += 256) {
            int row = c / CHR, cb = c - row * CHR;
            int gr = m0 + row; if (gr >= N_NODES) gr = N_NODES - 1;
            bf16x8 v = *(const bf16x8*)&A1[(size_t)gr * K1 + cb * 8];
            *(bf16x8*)&smem[row * RS + ((cb * 16) ^ ((row & 7) << 4))] = v;
        }
        __syncthreads();
        const int KB = K1 >> 5;
        for (int k0 = 0; k0 < KB; ++k0) {
            bf16x8 a = *(const bf16x8*)&smem[rw * RS + ((k0 * 64 + hi * 16) ^ swz)];
            const ushort_t* wb = Wp1 + ((size_t)(k0 * 48) * 64 + l) * 8;
#pragma unroll
            for (int j = 0; j < 4; ++j) {
                bf16x8 b0 = *(const bf16x8*)&wb[(size_t)(otb + j) * 512];
                aR[j] = __builtin_amdgcn_mfma_f32_16x16x32_bf16(a, b0, aR[j], 0, 0, 0);
                bf16x8 b1 = *(const bf16x8*)&wb[(size_t)(16 + otb + j) * 512];
                aZ[j] = __builtin_amdgcn_mfma_f32_16x16x32_bf16(a, b1, aZ[j], 0, 0, 0);
                bf16x8 b2 = *(const bf16x8*)&wb[(size_t)(32 + otb + j) * 512];
                aN[j] = __builtin_amdgcn_mfma_f32_16x16x32_bf16(a, b2, aN[j], 0, 0, 0);
            }
        }
    }
    __syncthreads();
    // ---- stage A2 (K=256), K-loop 2 (hidden gates)
    {
        for (int c = tid; c < 64 * 32; c += 256) {
            int row = c >> 5, cb = c & 31;
            int gr = m0 + row; if (gr >= N_NODES) gr = N_NODES - 1;
            bf16x8 v = *(const bf16x8*)&A2[(size_t)gr * 256 + cb * 8];
            *(bf16x8*)&smem[row * 512 + ((cb * 16) ^ ((row & 7) << 4))] = v;
        }
        __syncthreads();
        for (int k0 = 0; k0 < 8; ++k0) {
            bf16x8 a = *(const bf16x8*)&smem[rw * 512 + ((k0 * 64 + hi * 16) ^ swz)];
            const ushort_t* wb = Wp2 + ((size_t)(k0 * 48) * 64 + l) * 8;
#pragma unroll
            for (int j = 0; j < 4; ++j) {
                bf16x8 b0 = *(const bf16x8*)&wb[(size_t)(otb + j) * 512];
                bR[j] = __builtin_amdgcn_mfma_f32_16x16x32_bf16(a, b0, bR[j], 0, 0, 0);
                bf16x8 b1 = *(const bf16x8*)&wb[(size_t)(16 + otb + j) * 512];
                bZ[j] = __builtin_amdgcn_mfma_f32_16x16x32_bf16(a, b1, bZ[j], 0, 0, 0);
                bf16x8 b2 = *(const bf16x8*)&wb[(size_t)(32 + otb + j) * 512];
                bN[j] = __builtin_amdgcn_mfma_f32_16x16x32_bf16(a, b2, bN[j], 0, 0, 0);
            }
        }
    }
    // ---- GRU combine epilogue
    const int c0 = l & 15;
    const int r0 = m0 + wid * 16 + hi * 4;
#pragma unroll
    for (int j = 0; j < 4; ++j) {
        int col = n0 + j * 16 + c0;
        float br_ = bih[col], bz_ = bih[256 + col], bn_ = bih[512 + col];
        float cr_ = bhh[col], cz_ = bhh[256 + col], cn_ = bhh[512 + col];
#pragma unroll
        for (int r = 0; r < 4; ++r) {
            int gr = r0 + r;
            if (gr >= N_NODES) continue;
            float ir = aR[j][r] + br_, iz = aZ[j][r] + bz_, in_ = aN[j][r] + bn_;
            float hr = bR[j][r] + cr_, hz = bZ[j][r] + cz_, hn = bN[j][r] + cn_;
            float h = hf[(size_t)gr * 256 + col];
            float rg = 1.f / (1.f + expf(-(ir + hr)));
            float zg = 1.f / (1.f + expf(-(iz + hz)));
            float ng = tanhf(in_ + rg * hn);
            float v = (1.f - zg) * ng + zg * h;
            houtf[(size_t)gr * 256 + col] = v;
            houtb[(size_t)gr * 256 + col] = f2bf(v);
        }
    }
}

// z = mu + eps * exp(0.5*log_var)
__global__ void z_kernel(const float* __restrict__ mu, const float* __restrict__ lv,
                         const float* __restrict__ eps, float* __restrict__ z)
{
    int idx = blockIdx.x * 256 + threadIdx.x;
    if (idx >= N_NODES * 64) return;
    z[idx] = mu[idx] + eps[idx] * expf(0.5f * lv[idx]);
}

extern "C" void kernel_launch(void* const* d_in, const int* in_sizes, int n_in,
                              void* d_out, int out_size, void* d_ws, size_t ws_size,
                              hipStream_t stream)
{
    const float* x      = (const float*)d_in[0];
    const float* t      = (const float*)d_in[1];
    const float* a      = (const float*)d_in[2];
    const float* eps    = (const float*)d_in[3];
    const int*   ei     = (const int*)d_in[4];
    const float* enc_w1 = (const float*)d_in[5];
    const float* enc_b1 = (const float*)d_in[6];
    const float* enc_w2 = (const float*)d_in[7];
    const float* enc_b2 = (const float*)d_in[8];
    const float* hi_w0  = (const float*)d_in[9];
    const float* hi_b0  = (const float*)d_in[10];
    const float* hi_w1  = (const float*)d_in[11];
    const float* hi_b1  = (const float*)d_in[12];
    const float* wih0   = (const float*)d_in[13];
    const float* whh0   = (const float*)d_in[14];
    const float* bih0   = (const float*)d_in[15];
    const float* bhh0   = (const float*)d_in[16];
    const float* wih1   = (const float*)d_in[17];
    const float* whh1   = (const float*)d_in[18];
    const float* bih1   = (const float*)d_in[19];
    const float* bhh1   = (const float*)d_in[20];
    const float* mu_w   = (const float*)d_in[21];
    const float* mu_b   = (const float*)d_in[22];
    const float* lv_w   = (const float*)d_in[23];
    const float* lv_b   = (const float*)d_in[24];

    // workspace layout (bytes), peak ~100.8 MB
    char* W = (char*)d_ws;
    ushort_t* pk     = (ushort_t*)(W + 0);           // 2,244,608 B packed weights
    float*    bpq    = (float*)(W + 2244608);        // 640 floats (bPQ | headbias)
    ushort_t* xbf    = (ushort_t*)(W + 2247680);     // 5,120,000
    float*    agg    = (float*)(W + 7368704);        // 20,480,000 (-> h0f)
    float*    h0f    = (float*)(W + 7368704);
    ushort_t* pqbf   = (ushort_t*)(W + 27848704);    // 20,480,000 (-> h1f)
    float*    h1f    = (float*)(W + 27848704);
    ushort_t* featbf = (ushort_t*)(W + 48328704);    // 11,520,000
    ushort_t* h0bf   = (ushort_t*)(W + 59848704);    // 10,240,000
    ushort_t* h1bf   = (ushort_t*)(W + 70088704);    // 10,240,000
    ushort_t* nh0bf  = (ushort_t*)(W + 80328704);    // 10,240,000
    ushort_t* nh1bf  = (ushort_t*)(W + 90568704);    // 10,240,000

    float* out_h0 = (float*)d_out;
    float* out_h1 = out_h0 + (size_t)N_NODES * 256;
    float* out_mu = out_h1 + (size_t)N_NODES * 256;
    float* out_lv = out_mu + (size_t)N_NODES * 64;
    float* out_z  = out_lv + (size_t)N_NODES * 64;

    dim3 blk(256);

    pack_all<<<dim3(108, 10), blk, 0, stream>>>(enc_w1, enc_b1, enc_w2, hi_w0, hi_w1,
                                                wih0, whh0, wih1, whh1, mu_w, lv_w,
                                                mu_b, lv_b, pk, bpq);
    xcvt<<<2500, blk, 0, stream>>>(x, xbf);
    hipMemsetAsync(agg, 0, (size_t)N_NODES * 256 * sizeof(float), stream);

    // PQ = xbf @ WPQ^T + bPQ -> bf16 [N,512]
    mgemm<128, 1><<<dim3(313, 4), blk, 0, stream>>>(xbf, 128, N_NODES, 128,
                                                    pk + 0, 32, bpq, nullptr, pqbf, 512);
    // edge layer2 + segment-max: 32 edges/block, 10000 blocks
    edge_mfma<<<10000, blk, 0, stream>>>(pqbf, ei, pk + 65536, enc_b2, agg);

    build_feat<<<22500, blk, 0, stream>>>(agg, t, a, featbf);

    // h0, h1 = tanh(feat @ hi_w^T + b)  (dual f32 + bf16)
    mgemm<128, 2><<<dim3(313, 2), blk, 0, stream>>>(featbf, 288, N_NODES, 288,
                                                    pk + 131072, 16, hi_b0, h0f, h0bf, 256);
    mgemm<128, 2><<<dim3(313, 2), blk, 0, stream>>>(featbf, 288, N_NODES, 288,
                                                    pk + 204800, 16, hi_b1, h1f, h1bf, 256);
    // fused GRU layers
    gru_fused<<<dim3(313, 4), blk, 0, stream>>>(featbf, 288, h0bf,
                                                pk + 278528, pk + 499712,
                                                bih0, bhh0, h0f, out_h0, nh0bf);
    gru_fused<<<dim3(313, 4), blk, 0, stream>>>(nh0bf, 256, h1bf,
                                                pk + 696320, pk + 892928,
                                                bih1, bhh1, h1f, out_h1, nh1bf);
    // fused heads: [mu | lv]
    mgemm<64, 3><<<dim3(313, 2), blk, 0, stream>>>(nh1bf, 256, N_NODES, 256,
                                                   pk + 1089536, 8, bpq + 512,
                                                   out_mu, nullptr, 64);
    z_kernel<<<5000, blk, 0, stream>>>(out_mu, out_lv, eps, out_z);
}